// Round 9
// baseline (197.666 us; speedup 1.0000x reference)
//
#include <hip/hip_runtime.h>

// SelfAttention3D: B=4, C=128, N=16^3=4096, Cqk=16.
// R13: in-register P at R12's no-spill footprint. 512 blocks x 512 thr;
// wave (kg,cg) = key-quarter (1024 keys = 16 tiles of 64) x channel-half
// (64 ch). Per tile: swapped QK (s = mfma(K,Q), R7-verified exchange:
// cvt_pk -> cndmask + 4 shfl builds the PV A-frag in-register) -> PV.
// NO in-loop LDS, NO in-loop barriers, independent waves (R5's property)
// at acc[8]+vf[8] footprint (~74 VGPR + 32 AGPR, fits the 128 wall).
// QK MFMA duplicated per cg pair (QK = 1/9 of FLOPs). kf[4] single-buffer
// reload mid-tile (R9 pattern). L lane-local (Lq), transposed at end.
// Keeps: contiguous 16KB V tiles, exp2 w/ log2e folded into Q, XCD pin.

typedef __attribute__((ext_vector_type(8))) short short8;
typedef __attribute__((ext_vector_type(4))) float f32x4;
typedef __attribute__((ext_vector_type(4))) unsigned int u32x4;

#define NTOK 4096
#define CDIM 128
#define L2E 1.44269504088896340736f

__device__ __forceinline__ unsigned short f2bf(float f) {
  unsigned int u = __float_as_uint(f);
  return (unsigned short)((u + 0x7fffu + ((u >> 16) & 1u)) >> 16);
}

// ---------------------------------------------------------------------------
// Projection (unchanged from R12, harness-verified): q,k,v channel-GEMMs.
// qb,kb: [B][N][16] row per token. Q pre-scaled by log2(e).
// vb tiled: elem(b,c,m) = b*524288 + (m>>6)*8192
//           + ((c>>4)*2 + ((m>>5)&1))*512 + ((m>>3)&3)*128 + (c&15)*8 + (m&7)
// ---------------------------------------------------------------------------
__global__ __launch_bounds__(256) void sa3d_proj(
    const float* __restrict__ x,
    const float* __restrict__ Wq, const float* __restrict__ bq,
    const float* __restrict__ Wk, const float* __restrict__ bk,
    const float* __restrict__ Wv, const float* __restrict__ bv,
    unsigned short* __restrict__ qb, unsigned short* __restrict__ kb,
    unsigned short* __restrict__ vb)
{
  __shared__ unsigned short Wl[160 * 136];
  __shared__ unsigned short xT[64 * 136];
  const int tid = threadIdx.x;
  const int b = (blockIdx.x & 7) >> 1;
  const int nt = ((blockIdx.x >> 3) << 1) | (blockIdx.x & 1);  // [0,64)
  const int n0 = nt << 6;

  for (int i = 0; i < 80; ++i) {
    int idx = i * 256 + tid;
    int o = idx >> 7, c = idx & 127;
    float wv;
    if (o < 16)      wv = Wq[o * 128 + c] * L2E;   // fold log2e into Q
    else if (o < 32) wv = Wk[(o - 16) * 128 + c];
    else             wv = Wv[(o - 32) * 128 + c];
    Wl[o * 136 + c] = f2bf(wv);
  }
  {
    int nn = tid & 63, cg = tid >> 6;
    const float* xp = x + (size_t)b * CDIM * NTOK + n0 + nn;
    for (int cp = 0; cp < 16; ++cp) {
      int c = cg * 32 + cp * 2;
      float v0 = xp[(size_t)c * NTOK];
      float v1 = xp[(size_t)(c + 1) * NTOK];
      *(unsigned int*)&xT[nn * 136 + c] =
          (unsigned int)f2bf(v0) | ((unsigned int)f2bf(v1) << 16);
    }
  }
  __syncthreads();

  const int w = tid >> 6, lane = tid & 63;
  const int l15 = lane & 15, g = lane >> 4;

  short8 bfr[4];
#pragma unroll
  for (int ks = 0; ks < 4; ++ks)
    bfr[ks] = *(const short8*)&xT[(w * 16 + l15) * 136 + ks * 32 + g * 8];

  const int n = n0 + w * 16 + l15;
#pragma unroll
  for (int ot = 0; ot < 10; ++ot) {
    f32x4 acc = {};
#pragma unroll
    for (int ks = 0; ks < 4; ++ks) {
      short8 af = *(const short8*)&Wl[(ot * 16 + l15) * 136 + ks * 32 + g * 8];
      acc = __builtin_amdgcn_mfma_f32_16x16x32_bf16(af, bfr[ks], acc, 0, 0, 0);
    }
    int ob = ot * 16 + 4 * g;
    if (ot == 0) {
      unsigned int p0 = (unsigned int)f2bf(acc[0] + bq[ob] * L2E) |
                        ((unsigned int)f2bf(acc[1] + bq[ob + 1] * L2E) << 16);
      unsigned int p1 = (unsigned int)f2bf(acc[2] + bq[ob + 2] * L2E) |
                        ((unsigned int)f2bf(acc[3] + bq[ob + 3] * L2E) << 16);
      unsigned int* d = (unsigned int*)&qb[((size_t)b * NTOK + n) * 16 + ob];
      d[0] = p0; d[1] = p1;
    } else if (ot == 1) {
      int o2 = ob - 16;
      unsigned int p0 = (unsigned int)f2bf(acc[0] + bk[o2]) |
                        ((unsigned int)f2bf(acc[1] + bk[o2 + 1]) << 16);
      unsigned int p1 = (unsigned int)f2bf(acc[2] + bk[o2 + 2]) |
                        ((unsigned int)f2bf(acc[3] + bk[o2 + 3]) << 16);
      unsigned int* d = (unsigned int*)&kb[((size_t)b * NTOK + n) * 16 + o2];
      d[0] = p0; d[1] = p1;
    } else {
#pragma unroll
      for (int r = 0; r < 4; ++r) {
        int o = ob + r - 32;  // channel c in [0,128)
        size_t eidx = (size_t)(n >> 6) * 8192 +
                      (size_t)((o >> 4) * 2 + ((n >> 5) & 1)) * 512 +
                      (size_t)((n >> 3) & 3) * 128 + (o & 15) * 8 + (n & 7);
        vb[(size_t)b * (CDIM * NTOK) + eidx] = f2bf(acc[r] + bv[o]);
      }
    }
  }
}

// ---------------------------------------------------------------------------
// Flash attention. 512 blocks x 512 threads, NO in-loop barriers/LDS.
// Block: batch b=(bid&7)>>1 (XCD-pinned), 32 queries. Wave w: kg=w>>1
// (keys [kg*1024,+1024)), cg=w&1 (channels [cg*64,+64)). Per 64-key tile:
//   8 vf loads -> per 32-key half hc: 4 swapped-QK MFMA (D[k][q]) -> exp2
//   -> cvt_pk -> cndmask+4shfl => PV A-frag (R7-verified) -> 8 PV MFMA;
//   kf reload (next tile) between hc=1's QK and its PV.
// End: Lq lane-local -> xor/shfl transpose; LDS tree: kg-merge within cg;
// waves 0,1 do the epilogue (64 ch each).
// ---------------------------------------------------------------------------
__global__ __launch_bounds__(512, 2) void sa3d_attn(
    const unsigned short* __restrict__ qb, const unsigned short* __restrict__ kb,
    const unsigned short* __restrict__ vb,
    const float* __restrict__ x, const float* __restrict__ gamma,
    float* __restrict__ out)
{
  // LDS (post-loop only): [0,32768) 4 acc-reduce slots of 8 KB;
  //                       [32768,33792) L slots, 8 waves x 32 floats
  __shared__ __align__(16) unsigned char smem[33792];

  const int tid = threadIdx.x;
  const int w = tid >> 6, lane = tid & 63;
  const int l15 = lane & 15, g = lane >> 4;
  const int kg = w >> 1, cg = w & 1;
  const int b = (blockIdx.x & 7) >> 1;
  const int qt = ((blockIdx.x >> 3) << 1) | (blockIdx.x & 1);  // [0,128)
  const int q0 = qt << 5;

  float* LDp = (float*)(smem + 32768);

  const unsigned short* qbase = qb + (size_t)b * NTOK * 16;
  const unsigned short* kbase = kb + (size_t)b * NTOK * 16;
  const unsigned short* vbase = vb + (size_t)b * CDIM * NTOK;

  short8 aq[2] = {short8{}, short8{}};
#pragma unroll
  for (int qh = 0; qh < 2; ++qh)
    if (g < 2)
      aq[qh] = *(const short8*)&qbase[(size_t)(q0 + qh * 16 + l15) * 16 + g * 8];

  f32x4 acc[8];  // [qh*4 + ctl]; D[q=4g+r][c=ctl*16+l15] per qh
#pragma unroll
  for (int i = 0; i < 8; ++i) acc[i] = (f32x4){};
  float Lq[2] = {0.f, 0.f};  // per-lane: sum over this lane's keys, q=l15

  const int kv0 = kg << 10;                     // 1024 keys per kg
  const int voff = cg * 4096 + g * 128 + l15 * 8;
  const unsigned short* vtile = vbase + (size_t)kg * 16 * 8192;

  const bool hi32 = lane >= 32;                 // selects kt2 for this g
  const int srcb = l15 + ((g & 1) << 5);        // shuffle source base lane

  short8 kf[4];  // K fragments for the current 64-key tile (A-operand)

#define LOADK(TT)                                                             \
  {                                                                           \
    _Pragma("unroll") for (int j = 0; j < 4; ++j) {                           \
      kf[j] = short8{};                                                       \
      if (g < 2)                                                              \
        kf[j] = *(const short8*)&kbase[                                       \
            (size_t)(kv0 + ((TT) << 6) + j * 16 + l15) * 16 + g * 8];         \
    }                                                                         \
  }

  // One 32-key half: swapped QK -> exp2 -> cvt_pk -> shuffle-exchange -> pa.
  // s = mfma(K,Q): lane(l15,g) reg r = S[k=16*kt2+4g+r][q=l15].
  // pa[qh]: lane(l15,g) = P[q=l15][m=g*8..g*8+7] (A-frag), via
  // kt2-select on hi32 + words from lanes srcb, srcb+16. (R7-verified.)
#define QK_HALF(HC, PA)                                                       \
  {                                                                           \
    unsigned int cpk[2][2][2]; /* [qh][kt2][word] */                          \
    _Pragma("unroll") for (int kt2 = 0; kt2 < 2; ++kt2) {                     \
      _Pragma("unroll") for (int qh = 0; qh < 2; ++qh) {                      \
        f32x4 z = {};                                                         \
        f32x4 s = __builtin_amdgcn_mfma_f32_16x16x32_bf16(                    \
            kf[(HC) * 2 + kt2], aq[qh], z, 0, 0, 0);                          \
        float e0 = __builtin_exp2f(s[0]);                                     \
        float e1 = __builtin_exp2f(s[1]);                                     \
        float e2 = __builtin_exp2f(s[2]);                                     \
        float e3 = __builtin_exp2f(s[3]);                                     \
        Lq[qh] += (e0 + e1) + (e2 + e3);                                      \
        asm("v_cvt_pk_bf16_f32 %0, %1, %2"                                    \
            : "=v"(cpk[qh][kt2][0]) : "v"(e0), "v"(e1));                      \
        asm("v_cvt_pk_bf16_f32 %0, %1, %2"                                    \
            : "=v"(cpk[qh][kt2][1]) : "v"(e2), "v"(e3));                      \
      }                                                                       \
    }                                                                         \
    _Pragma("unroll") for (int qh = 0; qh < 2; ++qh) {                        \
      unsigned int selA = hi32 ? cpk[qh][1][0] : cpk[qh][0][0];               \
      unsigned int selB = hi32 ? cpk[qh][1][1] : cpk[qh][0][1];               \
      unsigned int w0 = (unsigned int)__shfl((int)selA, srcb);                \
      unsigned int w1 = (unsigned int)__shfl((int)selB, srcb);                \
      unsigned int w2 = (unsigned int)__shfl((int)selA, srcb + 16);           \
      unsigned int w3 = (unsigned int)__shfl((int)selB, srcb + 16);           \
      u32x4 pw = {w0, w1, w2, w3};                                            \
      PA[qh] = *(short8*)&pw;                                                 \
    }                                                                         \
  }

  // Iter T: vf loads -> hc0 QK -> hc0 PV -> hc1 QK -> kf<-K(T+1) -> hc1 PV.
#define SA_TILE(T, PREF)                                                      \
  {                                                                           \
    short8 vf[8];                                                             \
    {                                                                         \
      const unsigned short* vt = vtile + (size_t)(T) * 8192;                  \
      _Pragma("unroll") for (int f = 0; f < 8; ++f)                           \
        vf[f] = *(const short8*)&vt[f * 512 + voff];                          \
    }                                                                         \
    short8 pa[2];                                                             \
    QK_HALF(0, pa);                                                           \
    __builtin_amdgcn_s_setprio(1);                                            \
    _Pragma("unroll") for (int qh = 0; qh < 2; ++qh)                          \
      _Pragma("unroll") for (int ctl = 0; ctl < 4; ++ctl)                     \
        acc[qh * 4 + ctl] = __builtin_amdgcn_mfma_f32_16x16x32_bf16(          \
            pa[qh], vf[ctl * 2 + 0], acc[qh * 4 + ctl], 0, 0, 0);             \
    __builtin_amdgcn_s_setprio(0);                                            \
    QK_HALF(1, pa);                                                           \
    if (PREF) LOADK((T) + 1);                                                 \
    __builtin_amdgcn_s_setprio(1);                                            \
    _Pragma("unroll") for (int qh = 0; qh < 2; ++qh)                          \
      _Pragma("unroll") for (int ctl = 0; ctl < 4; ++ctl)                     \
        acc[qh * 4 + ctl] = __builtin_amdgcn_mfma_f32_16x16x32_bf16(          \
            pa[qh], vf[ctl * 2 + 1], acc[qh * 4 + ctl], 0, 0, 0);             \
    __builtin_amdgcn_s_setprio(0);                                            \
  }

  LOADK(0);
  SA_TILE(0, 1);  SA_TILE(1, 1);  SA_TILE(2, 1);  SA_TILE(3, 1);
  SA_TILE(4, 1);  SA_TILE(5, 1);  SA_TILE(6, 1);  SA_TILE(7, 1);
  SA_TILE(8, 1);  SA_TILE(9, 1);  SA_TILE(10, 1); SA_TILE(11, 1);
  SA_TILE(12, 1); SA_TILE(13, 1); SA_TILE(14, 1); SA_TILE(15, 0);
#undef SA_TILE
#undef QK_HALF
#undef LOADK

  // L: sum g-groups (all lanes then hold L[q=l15] for this wave's keys),
  // transpose to (g,r) layout, park in per-wave LDS slot.
  float Lp[2][4];
#pragma unroll
  for (int qh = 0; qh < 2; ++qh) {
    float v = Lq[qh];
    v += __shfl_xor(v, 16);
    v += __shfl_xor(v, 32);
#pragma unroll
    for (int r = 0; r < 4; ++r)
      Lp[qh][r] = __shfl(v, 4 * g + r);
  }
  if (l15 == 0) {
#pragma unroll
    for (int qh = 0; qh < 2; ++qh)
#pragma unroll
      for (int r = 0; r < 4; ++r)
        LDp[w * 32 + qh * 16 + 4 * g + r] = Lp[qh][r];
  }
  __syncthreads();

  // acc tree: kg-merge within cg (slots preserve cg pairing), R12 verbatim.
  const int rowb = lane * 128;
  const int sw = (l15 & 7) << 4;

#define ACC_STORE(i)                                                        \
  {                                                                         \
    char* base = (char*)smem + (i) * 8192 + rowb;                           \
    _Pragma("unroll") for (int j = 0; j < 8; ++j)                           \
        *(f32x4*)(base + ((j * 16) ^ sw)) = acc[j];                         \
  }
#define ACC_ADD(i)                                                          \
  {                                                                         \
    char* base = (char*)smem + (i) * 8192 + rowb;                           \
    _Pragma("unroll") for (int j = 0; j < 8; ++j)                           \
        acc[j] += *(const f32x4*)(base + ((j * 16) ^ sw));                  \
  }

  if (w >= 4) ACC_STORE(w - 4);
  __syncthreads();
  if (w < 4) ACC_ADD(w);
  __syncthreads();
  if (w == 2 || w == 3) ACC_STORE(w - 2);
  __syncthreads();

  if (w < 2) {
    ACC_ADD(w);
    float Lf[2][4] = {{0.f, 0.f, 0.f, 0.f}, {0.f, 0.f, 0.f, 0.f}};
#pragma unroll
    for (int w8 = 0; w8 < 8; ++w8)
#pragma unroll
      for (int qh = 0; qh < 2; ++qh)
#pragma unroll
        for (int r = 0; r < 4; ++r)
          Lf[qh][r] += LDp[w8 * 32 + qh * 16 + 4 * g + r];
    const float ga = gamma[0];
    float inv[2][4];
#pragma unroll
    for (int qh = 0; qh < 2; ++qh)
#pragma unroll
      for (int r = 0; r < 4; ++r) inv[qh][r] = 1.0f / Lf[qh][r];

    const float* xb = x + (size_t)b * CDIM * NTOK;
    float* ob = out + (size_t)b * CDIM * NTOK;
#pragma unroll
    for (int qh = 0; qh < 2; ++qh)
#pragma unroll
      for (int ctl = 0; ctl < 4; ++ctl) {
        int c = w * 64 + ctl * 16 + l15;   // cg == w for w in {0,1}
        size_t idx = (size_t)c * NTOK + q0 + qh * 16 + 4 * g;
        f32x4 xv = *(const f32x4*)&xb[idx];
        f32x4 o;
#pragma unroll
        for (int r = 0; r < 4; ++r)
          o[r] = ga * acc[qh * 4 + ctl][r] * inv[qh][r] + xv[r];
        *(f32x4*)&ob[idx] = o;
      }
  }
}

extern "C" void kernel_launch(void* const* d_in, const int* in_sizes, int n_in,
                              void* d_out, int out_size, void* d_ws, size_t ws_size,
                              hipStream_t stream) {
  const float* x     = (const float*)d_in[0];
  const float* Wq    = (const float*)d_in[1];
  const float* bq    = (const float*)d_in[2];
  const float* Wk    = (const float*)d_in[3];
  const float* bk    = (const float*)d_in[4];
  const float* Wv    = (const float*)d_in[5];
  const float* bv    = (const float*)d_in[6];
  const float* gamma = (const float*)d_in[7];

  unsigned short* qb = (unsigned short*)d_ws;          // 512 KB
  unsigned short* kb = qb + (size_t)4 * NTOK * 16;     // 512 KB
  unsigned short* vb = kb + (size_t)4 * NTOK * 16;     // 4 MB (tiled layout)
  float* outp = (float*)d_out;

  sa3d_proj<<<dim3(256), dim3(256), 0, stream>>>(x, Wq, bq, Wk, bk, Wv, bv,
                                                 qb, kb, vb);
  sa3d_attn<<<dim3(512), dim3(512), 0, stream>>>(qb, kb, vb, x, gamma, outp);
}